// Round 1
// 369.933 us; speedup vs baseline: 1.1146x; 1.1146x over previous
//
#include <hip/hip_runtime.h>
#include <hip/hip_bf16.h>

#define B_ 4
#define N_ 8192
#define M_ 2048
#define K_ 8

typedef __bf16 bf16x8 __attribute__((ext_vector_type(8)));
typedef __bf16 bf16x4 __attribute__((ext_vector_type(4)));
typedef float  floatx4 __attribute__((ext_vector_type(4)));

// ---------------------------------------------------------------------------
// Cast all MLP weights fp32 -> bf16 once. w1_0 [128,259] zero-padded to
// [128,288]. Flat segments: 36864 | 16384 | 32768 | 131072 = 217088 elems.
// ---------------------------------------------------------------------------
__global__ __launch_bounds__(256) void prep_weights(
    const float* __restrict__ w10, const float* __restrict__ w11,
    const float* __restrict__ w12, const float* __restrict__ w20,
    __bf16* __restrict__ w0p, __bf16* __restrict__ w11b,
    __bf16* __restrict__ w12b, __bf16* __restrict__ w20b)
{
  int t = blockIdx.x * 256 + threadIdx.x;
  if (t < 36864) {
    int o = t / 288, c = t - o * 288;
    w0p[t] = (c < 259) ? (__bf16)w10[o * 259 + c] : (__bf16)0.0f;
  } else if (t < 53248) {
    int i = t - 36864; w11b[i] = (__bf16)w11[i];
  } else if (t < 86016) {
    int i = t - 53248; w12b[i] = (__bf16)w12[i];
  } else if (t < 217088) {
    int i = t - 86016; w20b[i] = (__bf16)w20[i];
  }
}

// ---------------------------------------------------------------------------
// [B,C,L] fp32 -> [B,L,C] bf16 transpose+cast (C,L multiples of 32)
// ---------------------------------------------------------------------------
__global__ __launch_bounds__(256) void transpose_cast(
    const float* __restrict__ in, __bf16* __restrict__ out, int C, int L)
{
  __shared__ float tile[32][33];
  const int b = blockIdx.z;
  const int c0 = blockIdx.y * 32, l0 = blockIdx.x * 32;
  const int tx = threadIdx.x & 31, ty = threadIdx.x >> 5;   // ty 0..7
  const float* src = in + (size_t)b * C * L;
  #pragma unroll
  for (int i = 0; i < 4; i++)
    tile[ty + 8 * i][tx] = src[(size_t)(c0 + ty + 8 * i) * L + l0 + tx];
  __syncthreads();
  __bf16* dst = out + (size_t)b * L * C;
  #pragma unroll
  for (int i = 0; i < 4; i++)
    dst[(size_t)(l0 + ty + 8 * i) * C + c0 + tx] = (__bf16)tile[tx][ty + 8 * i];
}

// ---------------------------------------------------------------------------
// KNN: 64 points/block, 4 threads/point. Candidate assignment INTERLEAVED
// (thread t scans c = t + 4*j): the 4 distinct LDS addresses per wave read
// are now consecutive 16B chunks (banks spread) instead of t*8192B apart
// (all bank 0 -> 4-way conflict on every read of the scan loop).
// Per-thread stream is still index-ascending, so strict-< insertion keeps
// the earliest index on ties, and the final lexicographic (d,idx) 4-way
// merge reproduces lax.top_k tie-breaking exactly.
// ---------------------------------------------------------------------------
__global__ __launch_bounds__(256) void knn_kernel(
    const float* __restrict__ pos1, const float* __restrict__ pos2,
    int* __restrict__ idx_out)
{
  __shared__ floatx4 P[M_];        // 32 KB: (x,y,z,r) per candidate
  __shared__ float md[64][33];     // 4 sorted lists x 8 per point (+pad)
  __shared__ int   mi[64][33];
  const int b = blockIdx.y;
  const int n0 = blockIdx.x * 64;
  const int tid = threadIdx.x;

  const float* p2 = pos2 + b * 3 * M_;
  for (int i = tid; i < M_; i += 256) {
    float x = p2[i], y = p2[M_ + i], z = p2[2 * M_ + i];
    floatx4 q;
    q[0] = x; q[1] = y; q[2] = z;
    q[3] = __fadd_rn(__fadd_rn(__fmul_rn(x, x), __fmul_rn(y, y)), __fmul_rn(z, z));
    P[i] = q;
  }
  __syncthreads();

  const int p = tid >> 2, t = tid & 3;
  const int n = n0 + p;
  const float* p1 = pos1 + b * 3 * N_;
  const float x1 = p1[n], y1 = p1[N_ + n], z1 = p1[2 * N_ + n];
  const float r1 = __fadd_rn(__fadd_rn(__fmul_rn(x1, x1), __fmul_rn(y1, y1)),
                             __fmul_rn(z1, z1));

  float bd[K_]; int bi[K_];
  #pragma unroll
  for (int j = 0; j < K_; j++) { bd[j] = 3.0e38f; bi[j] = 0; }

  for (int j = 0; j < 512; j += 4) {
    float d4[4]; int c4[4];
    #pragma unroll
    for (int jj = 0; jj < 4; jj++) {
      const int c = t + 4 * (j + jj);         // interleaved candidate index
      floatx4 q = P[c];
      float dot = __fadd_rn(__fadd_rn(__fmul_rn(x1, q[0]), __fmul_rn(y1, q[1])),
                            __fmul_rn(z1, q[2]));
      d4[jj] = __fsub_rn(__fadd_rn(r1, q[3]), __fmul_rn(2.0f, dot));
      c4[jj] = c;
    }
    #pragma unroll
    for (int jj = 0; jj < 4; jj++) {
      float d = d4[jj];
      if (d < bd[K_ - 1]) {          // strict <: equal-d keeps earlier index
        float cd = d; int ci = c4[jj];
        #pragma unroll
        for (int q = 0; q < K_; q++) {
          bool lt = (cd < bd[q]);
          float nd = lt ? cd : bd[q];  int ni = lt ? ci : bi[q];
          float od = lt ? bd[q] : cd;  int oi = lt ? bi[q] : ci;
          bd[q] = nd; bi[q] = ni; cd = od; ci = oi;
        }
      }
    }
  }
  #pragma unroll
  for (int r = 0; r < K_; r++) { md[p][t * 8 + r] = bd[r]; mi[p][t * 8 + r] = bi[r]; }
  __syncthreads();

  if (tid < 64) {
    int h[4] = {0, 0, 0, 0};
    int* o = idx_out + ((size_t)(b * N_ + n0 + tid)) * K_;
    for (int r = 0; r < K_; r++) {
      float bdv = 3.3e38f; int bii = 0x7fffffff; int bt = 0;
      #pragma unroll
      for (int tt = 0; tt < 4; tt++) {
        if (h[tt] < 8) {
          float dv = md[tid][tt * 8 + h[tt]];
          int   iv = mi[tid][tt * 8 + h[tt]];
          if (dv < bdv || (dv == bdv && iv < bii)) { bdv = dv; bii = iv; bt = tt; }
        }
      }
      #pragma unroll
      for (int tt = 0; tt < 4; tt++) h[tt] += (bt == tt);
      o[r] = bii;
    }
  }
}

// ---------------------------------------------------------------------------
// LDS-input MFMA layer with next-kstep register prefetch (weights global,
// X from LDS). W-major: D rows = out cols, D cols = points. PT=4 x WT=2,
// weights read once per block. Packed bf16x4 epilogue.
// Fragment maps (gfx950, HW-verified): A[m=lane&15][k=quad*8+j],
// B[n=lane&15][k=quad*8+j], D[row=quad*4+reg][col=lane&15].
// ---------------------------------------------------------------------------
template <int KSTEPS>
__device__ __forceinline__ void mfma_layer_lds(
    const __bf16* X, const __bf16* W, int wstride,
    const float* sv, const float* bv,
    __bf16* Y, int ycolbase, int c0, int lane)
{
  const int lrow = lane & 15, quad = lane >> 4;
  floatx4 acc[4][2];
  const floatx4 fz = {0.f, 0.f, 0.f, 0.f};
  #pragma unroll
  for (int pt = 0; pt < 4; pt++) { acc[pt][0] = fz; acc[pt][1] = fz; }

  bf16x8 wf0 = *(const bf16x8*)(W + (size_t)(c0 + lrow) * wstride + quad * 8);
  bf16x8 wf1 = *(const bf16x8*)(W + (size_t)(c0 + 16 + lrow) * wstride + quad * 8);
  bf16x8 xf[4];
  #pragma unroll
  for (int pt = 0; pt < 4; pt++)
    xf[pt] = *(const bf16x8*)(X + (pt * 16 + lrow) * 136 + quad * 8);

  #pragma unroll
  for (int ks = 0; ks < KSTEPS; ks++) {
    bf16x8 wn0, wn1, xn[4];
    if (ks + 1 < KSTEPS) {
      const int kn = (ks + 1) * 32 + quad * 8;
      wn0 = *(const bf16x8*)(W + (size_t)(c0 + lrow) * wstride + kn);
      wn1 = *(const bf16x8*)(W + (size_t)(c0 + 16 + lrow) * wstride + kn);
      #pragma unroll
      for (int pt = 0; pt < 4; pt++)
        xn[pt] = *(const bf16x8*)(X + (pt * 16 + lrow) * 136 + kn);
    }
    #pragma unroll
    for (int pt = 0; pt < 4; pt++) {
      acc[pt][0] = __builtin_amdgcn_mfma_f32_16x16x32_bf16(wf0, xf[pt], acc[pt][0], 0, 0, 0);
      acc[pt][1] = __builtin_amdgcn_mfma_f32_16x16x32_bf16(wf1, xf[pt], acc[pt][1], 0, 0, 0);
    }
    if (ks + 1 < KSTEPS) {
      wf0 = wn0; wf1 = wn1;
      #pragma unroll
      for (int pt = 0; pt < 4; pt++) xf[pt] = xn[pt];
    }
  }

  #pragma unroll
  for (int pt = 0; pt < 4; pt++) {
    #pragma unroll
    for (int wt = 0; wt < 2; wt++) {
      const int colg = c0 + wt * 16 + quad * 4;    // 4 consecutive out cols
      floatx4 s4 = *(const floatx4*)(sv + colg);
      floatx4 b4 = *(const floatx4*)(bv + colg);
      bf16x4 pk;
      #pragma unroll
      for (int r = 0; r < 4; r++) {
        float v = acc[pt][wt][r] * s4[r] + b4[r];
        pk[r] = (__bf16)(v > 0.f ? v : 0.f);
      }
      *(bf16x4*)(Y + (pt * 16 + lrow) * 136 + (colg - ycolbase)) = pk;
    }
  }
}

// ---------------------------------------------------------------------------
// MLP1 v2: all 64 gathered f2t rows are STAGED ONCE into LDS (32 KB) via
// global_load_lds width-16 at block start — the L2 gather latency is paid
// once behind one barrier instead of once per L0 k-step per wave (the old
// 1-step register prefetch was defeated by the 64-VGPR allocation anyway).
// DMA dest is linear (rule: wave-uniform base + lane*16); bank-conflict-free
// reads come from XOR-swizzling the per-lane GLOBAL source chunk by (row&7)
// and applying the same XOR on the ds_read_b128 side (T2 both-sides rule).
// Y1 aliases the X stage (dead after L0): LDS = 32K + 17.4K + 1.3K = 51.5 KB
// -> 3 blocks/CU; __launch_bounds__(256,3) lifts the VGPR cap to ~170 so the
// weight prefetch stays in registers.
// ---------------------------------------------------------------------------
__global__ __launch_bounds__(256, 3) void mlp1_kernel(
    const float* __restrict__ pos1, const float* __restrict__ pos2,
    const int* __restrict__ idx, const __bf16* __restrict__ f2t,
    const __bf16* __restrict__ w0p, const float* __restrict__ s10, const float* __restrict__ b10,
    const __bf16* __restrict__ w11b, const float* __restrict__ s11, const float* __restrict__ b11,
    const __bf16* __restrict__ w12b, const float* __restrict__ s12, const float* __restrict__ b12,
    __bf16* __restrict__ maxed)
{
  __shared__ __align__(16) __bf16 Xs[64 * 256];   // 32 KB staged gathers (swizzled); Y1 aliases
  __shared__ __align__(16) __bf16 Y0[64 * 136];   // 17.4 KB
  __shared__ int mrow[64];
  __shared__ __align__(16) float dp[64][4];
  __bf16* const Y1 = Xs;                          // X dead after L0

  const int b = blockIdx.y;
  const int n0 = blockIdx.x * 8;
  const int tid = threadIdx.x;
  const int wave = tid >> 6, lane = tid & 63;
  const int lrow = lane & 15, quad = lane >> 4;
  const int c0 = 32 * wave;

  // prologue: neighbor index + posdiff per row (row r = point g, rank k)
  if (tid < 64) {
    const int r = tid, g = r >> 3;
    const int m = idx[(b * N_ + n0) * K_ + r];
    mrow[r] = m;
    const int n = n0 + g;
    dp[r][0] = pos2[b * 3 * M_ + m]          - pos1[b * 3 * N_ + n];
    dp[r][1] = pos2[b * 3 * M_ + M_ + m]     - pos1[b * 3 * N_ + N_ + n];
    dp[r][2] = pos2[b * 3 * M_ + 2 * M_ + m] - pos1[b * 3 * N_ + 2 * N_ + n];
    dp[r][3] = 0.f;
  }
  __syncthreads();

  // ---- stage: wave w DMAs rows [16w,16w+16) of the gather into Xs.
  // Per instr: lanes 0-31 = row r, lanes 32-63 = row r+1 (1 KB linear dest).
  // Source chunk index XORed by (row&7) so swizzled reads are conflict-free.
  {
    const int r0 = wave * 16;
    const int half = lane >> 5;          // which row of the pair
    const int ch = lane & 31;            // 16B chunk within the 512B row
    #pragma unroll
    for (int i = 0; i < 8; i++) {
      const int r = r0 + 2 * i + half;
      const int m = mrow[r];
      const char* src = (const char*)f2t
          + (((size_t)(b * M_ + m)) << 9)
          + ((ch << 4) ^ ((r & 7) << 4));
      __builtin_amdgcn_global_load_lds(
          (const __attribute__((address_space(1))) unsigned int*)src,
          (__attribute__((address_space(3))) unsigned int*)(Xs + (r0 + 2 * i) * 256),
          16, 0, 0);
    }
  }

  // last k-step fragment (posdiff) built in registers while DMA in flight
  bf16x8 xlast[4];
  #pragma unroll
  for (int pt = 0; pt < 4; pt++) {
    bf16x8 v = {};
    if (quad == 0) {               // k=256..263: [dx,dy,dz,0,...]
      floatx4 d = *(const floatx4*)(&dp[pt * 16 + lrow][0]);
      v[0] = (__bf16)d[0]; v[1] = (__bf16)d[1]; v[2] = (__bf16)d[2];
    }
    xlast[pt] = v;                 // quads 1-3 zero (w0p zero-padded too)
  }

  // W k-step-0 fragments issued before the barrier (L1/L2-resident)
  bf16x8 wf0 = *(const bf16x8*)(w0p + (size_t)(c0 + lrow) * 288 + quad * 8);
  bf16x8 wf1 = *(const bf16x8*)(w0p + (size_t)(c0 + 16 + lrow) * 288 + quad * 8);

  __syncthreads();                 // drains the global_load_lds DMA

  // ---- L0: K=288 = 8 LDS ksteps + posdiff step. Out -> Y0.
  {
    floatx4 acc[4][2];
    const floatx4 fz = {0.f, 0.f, 0.f, 0.f};
    #pragma unroll
    for (int pt = 0; pt < 4; pt++) { acc[pt][0] = fz; acc[pt][1] = fz; }

    const int swz = (lrow & 7) << 4;     // byte XOR within a 512B row
    bf16x8 xf[4];
    #pragma unroll
    for (int pt = 0; pt < 4; pt++)
      xf[pt] = *(const bf16x8*)((const char*)Xs + (pt * 16 + lrow) * 512
                                + ((quad * 16) ^ swz));

    #pragma unroll
    for (int ks = 0; ks < 9; ks++) {
      bf16x8 wn0, wn1, xn[4];
      if (ks < 8) {
        const int kn = (ks + 1) * 32 + quad * 8;
        wn0 = *(const bf16x8*)(w0p + (size_t)(c0 + lrow) * 288 + kn);
        wn1 = *(const bf16x8*)(w0p + (size_t)(c0 + 16 + lrow) * 288 + kn);
        if (ks < 7) {
          const int kb = ((ks + 1) * 64 + quad * 16) ^ swz;
          #pragma unroll
          for (int pt = 0; pt < 4; pt++)
            xn[pt] = *(const bf16x8*)((const char*)Xs + (pt * 16 + lrow) * 512 + kb);
        } else {
          #pragma unroll
          for (int pt = 0; pt < 4; pt++) xn[pt] = xlast[pt];
        }
      }
      #pragma unroll
      for (int pt = 0; pt < 4; pt++) {
        acc[pt][0] = __builtin_amdgcn_mfma_f32_16x16x32_bf16(wf0, xf[pt], acc[pt][0], 0, 0, 0);
        acc[pt][1] = __builtin_amdgcn_mfma_f32_16x16x32_bf16(wf1, xf[pt], acc[pt][1], 0, 0, 0);
      }
      if (ks < 8) {
        wf0 = wn0; wf1 = wn1;
        #pragma unroll
        for (int pt = 0; pt < 4; pt++) xf[pt] = xn[pt];
      }
    }
    #pragma unroll
    for (int pt = 0; pt < 4; pt++) {
      #pragma unroll
      for (int wt = 0; wt < 2; wt++) {
        const int colg = c0 + wt * 16 + quad * 4;
        floatx4 s4 = *(const floatx4*)(s10 + colg);
        floatx4 b4 = *(const floatx4*)(b10 + colg);
        bf16x4 pk;
        #pragma unroll
        for (int r = 0; r < 4; r++) {
          float v = acc[pt][wt][r] * s4[r] + b4[r];
          pk[r] = (__bf16)(v > 0.f ? v : 0.f);
        }
        *(bf16x4*)(Y0 + (pt * 16 + lrow) * 136 + colg) = pk;
      }
    }
  }
  __syncthreads();

  // ---- L1: 128 -> 128, Y0 -> Y1 (aliases the now-dead X stage)
  mfma_layer_lds<4>(Y0, w11b, 128, s11, b11, Y1, 0, c0, lane);
  __syncthreads();

  // ---- L2: 128 -> 256 in two 128-col passes (out -> Y0), maxpool K=8
  #pragma unroll
  for (int p = 0; p < 2; p++) {
    mfma_layer_lds<4>(Y1, w12b, 128, s12, b12, Y0, 128 * p, 128 * p + c0, lane);
    __syncthreads();
    // vectorized maxpool: 128 threads x 8 cols, b128 LDS reads + 16B store
    if (tid < 128) {
      const int g = tid >> 4, cb = (tid & 15) * 8;
      bf16x8 v0 = *(const bf16x8*)(Y0 + (g * 8) * 136 + cb);
      float fmx[8];
      #pragma unroll
      for (int j = 0; j < 8; j++) fmx[j] = (float)v0[j];
      #pragma unroll
      for (int k = 1; k < 8; k++) {
        bf16x8 v = *(const bf16x8*)(Y0 + (g * 8 + k) * 136 + cb);
        #pragma unroll
        for (int j = 0; j < 8; j++) {
          float f = (float)v[j];
          fmx[j] = f > fmx[j] ? f : fmx[j];
        }
      }
      bf16x8 o;
      #pragma unroll
      for (int j = 0; j < 8; j++) o[j] = (__bf16)fmx[j];
      *(bf16x8*)(maxed + ((size_t)(b * N_ + n0 + g)) * 256 + 128 * p + cb) = o;
    }
    __syncthreads();
  }
}

// ---------------------------------------------------------------------------
// MLP2: 32 rows x 128 out-cols per block, grid (1024, 2) = 2048 blocks.
// A = [maxed|f1t] bf16 contiguous, B = w20b [256][512]. Next-kstep register
// prefetch. Out fp32 floatx4.
// ---------------------------------------------------------------------------
__global__ __launch_bounds__(256, 6) void mlp2_kernel(
    const __bf16* __restrict__ maxed, const __bf16* __restrict__ f1t,
    const __bf16* __restrict__ w20b, const float* __restrict__ s20,
    const float* __restrict__ b20, float* __restrict__ out)
{
  const int rows0 = blockIdx.x * 32;           // b*N + n
  const int b = rows0 >> 13;
  const int nbase = rows0 & (N_ - 1);
  const int tid = threadIdx.x;
  const int wave = tid >> 6, lane = tid & 63;
  const int lrow = lane & 15, quad = lane >> 4;
  const int c0 = 128 * blockIdx.y + 32 * wave;
  const floatx4 fz = {0.f, 0.f, 0.f, 0.f};

  floatx4 acc[2][2];
  acc[0][0] = fz; acc[0][1] = fz; acc[1][0] = fz; acc[1][1] = fz;

  auto aptr = [&](int ks, int mt) -> const __bf16* {
    const int k = ks * 32 + quad * 8;
    return (ks < 8) ? (maxed + (size_t)(rows0 + mt * 16 + lrow) * 256 + k)
                    : (f1t + (size_t)(rows0 + mt * 16 + lrow) * 256 + (k - 256));
  };

  bf16x8 w0 = *(const bf16x8*)(w20b + (size_t)(c0 + lrow) * 512 + quad * 8);
  bf16x8 w1 = *(const bf16x8*)(w20b + (size_t)(c0 + 16 + lrow) * 512 + quad * 8);
  bf16x8 a0 = *(const bf16x8*)aptr(0, 0);
  bf16x8 a1 = *(const bf16x8*)aptr(0, 1);

  #pragma unroll
  for (int ks = 0; ks < 16; ks++) {
    bf16x8 wn0, wn1, an0, an1;
    if (ks < 15) {
      const int kn = (ks + 1) * 32 + quad * 8;
      wn0 = *(const bf16x8*)(w20b + (size_t)(c0 + lrow) * 512 + kn);
      wn1 = *(const bf16x8*)(w20b + (size_t)(c0 + 16 + lrow) * 512 + kn);
      an0 = *(const bf16x8*)aptr(ks + 1, 0);
      an1 = *(const bf16x8*)aptr(ks + 1, 1);
    }
    acc[0][0] = __builtin_amdgcn_mfma_f32_16x16x32_bf16(a0, w0, acc[0][0], 0, 0, 0);
    acc[0][1] = __builtin_amdgcn_mfma_f32_16x16x32_bf16(a0, w1, acc[0][1], 0, 0, 0);
    acc[1][0] = __builtin_amdgcn_mfma_f32_16x16x32_bf16(a1, w0, acc[1][0], 0, 0, 0);
    acc[1][1] = __builtin_amdgcn_mfma_f32_16x16x32_bf16(a1, w1, acc[1][1], 0, 0, 0);
    if (ks < 15) { w0 = wn0; w1 = wn1; a0 = an0; a1 = an1; }
  }

  #pragma unroll
  for (int ct = 0; ct < 2; ct++) {
    const int col = c0 + ct * 16 + lrow;
    const float s = s20[col];
    const float bb = b20[col];
    #pragma unroll
    for (int mt = 0; mt < 2; mt++) {
      floatx4 pk;
      #pragma unroll
      for (int r = 0; r < 4; r++) {
        float v = acc[mt][ct][r] * s + bb;
        pk[r] = v > 0.f ? v : 0.f;
      }
      const int n = nbase + mt * 16 + quad * 4;
      *(floatx4*)(out + ((size_t)(b * 256 + col)) * N_ + n) = pk;
    }
  }
}

// ---------------------------------------------------------------------------
extern "C" void kernel_launch(void* const* d_in, const int* in_sizes, int n_in,
                              void* d_out, int out_size, void* d_ws, size_t ws_size,
                              hipStream_t stream)
{
  const float* pos1     = (const float*)d_in[0];
  const float* pos2     = (const float*)d_in[1];
  const float* feature1 = (const float*)d_in[2];
  const float* feature2 = (const float*)d_in[3];
  const float* w1_0 = (const float*)d_in[4];
  const float* s1_0 = (const float*)d_in[5];
  const float* b1_0 = (const float*)d_in[6];
  const float* w1_1 = (const float*)d_in[7];
  const float* s1_1 = (const float*)d_in[8];
  const float* b1_1 = (const float*)d_in[9];
  const float* w1_2 = (const float*)d_in[10];
  const float* s1_2 = (const float*)d_in[11];
  const float* b1_2 = (const float*)d_in[12];
  const float* w2_0 = (const float*)d_in[13];
  const float* s2_0 = (const float*)d_in[14];
  const float* b2_0 = (const float*)d_in[15];

  // Workspace layout (39,231,488 B total)
  char* ws = (char*)d_ws;
  int*    idx   = (int*)(ws);                    //  1,048,576 @ 0
  __bf16* f2t   = (__bf16*)(ws + 1048576);       //  4,194,304
  __bf16* f1t   = (__bf16*)(ws + 5242880);       // 16,777,216
  __bf16* maxed = (__bf16*)(ws + 22020096);      // 16,777,216
  __bf16* w0p   = (__bf16*)(ws + 38797312);      //     73,728
  __bf16* w11b  = (__bf16*)(ws + 38871040);      //     32,768
  __bf16* w12b  = (__bf16*)(ws + 38903808);      //     65,536
  __bf16* w20b  = (__bf16*)(ws + 38969344);      //    262,144

  prep_weights<<<dim3(848), 256, 0, stream>>>(w1_0, w1_1, w1_2, w2_0,
                                              w0p, w11b, w12b, w20b);
  transpose_cast<<<dim3(M_ / 32, 8, B_), 256, 0, stream>>>(feature2, f2t, 256, M_);
  transpose_cast<<<dim3(N_ / 32, 8, B_), 256, 0, stream>>>(feature1, f1t, 256, N_);
  knn_kernel<<<dim3(N_ / 64, B_), 256, 0, stream>>>(pos1, pos2, idx);
  mlp1_kernel<<<dim3(N_ / 8, B_), 256, 0, stream>>>(
      pos1, pos2, idx, f2t, w0p, s1_0, b1_0, w11b, s1_1, b1_1, w12b, s1_2, b1_2, maxed);
  mlp2_kernel<<<dim3(1024, 2), 256, 0, stream>>>(maxed, f1t, w20b, s2_0, b2_0,
                                                 (float*)d_out);
}

// Round 2
// 339.958 us; speedup vs baseline: 1.2129x; 1.0882x over previous
//
#include <hip/hip_runtime.h>
#include <hip/hip_bf16.h>

#define B_ 4
#define N_ 8192
#define M_ 2048
#define K_ 8

typedef __bf16 bf16x8 __attribute__((ext_vector_type(8)));
typedef __bf16 bf16x4 __attribute__((ext_vector_type(4)));
typedef float  floatx4 __attribute__((ext_vector_type(4)));
typedef unsigned long long u64k;

// ---------------------------------------------------------------------------
// Cast all MLP weights fp32 -> bf16 once. w1_0 [128,259] zero-padded to
// [128,288]. Flat segments: 36864 | 16384 | 32768 | 131072 = 217088 elems.
// ---------------------------------------------------------------------------
__global__ __launch_bounds__(256) void prep_weights(
    const float* __restrict__ w10, const float* __restrict__ w11,
    const float* __restrict__ w12, const float* __restrict__ w20,
    __bf16* __restrict__ w0p, __bf16* __restrict__ w11b,
    __bf16* __restrict__ w12b, __bf16* __restrict__ w20b)
{
  int t = blockIdx.x * 256 + threadIdx.x;
  if (t < 36864) {
    int o = t / 288, c = t - o * 288;
    w0p[t] = (c < 259) ? (__bf16)w10[o * 259 + c] : (__bf16)0.0f;
  } else if (t < 53248) {
    int i = t - 36864; w11b[i] = (__bf16)w11[i];
  } else if (t < 86016) {
    int i = t - 53248; w12b[i] = (__bf16)w12[i];
  } else if (t < 217088) {
    int i = t - 86016; w20b[i] = (__bf16)w20[i];
  }
}

// ---------------------------------------------------------------------------
// [B,C,L] fp32 -> [B,L,C] bf16 transpose+cast (C,L multiples of 32)
// ---------------------------------------------------------------------------
__global__ __launch_bounds__(256) void transpose_cast(
    const float* __restrict__ in, __bf16* __restrict__ out, int C, int L)
{
  __shared__ float tile[32][33];
  const int b = blockIdx.z;
  const int c0 = blockIdx.y * 32, l0 = blockIdx.x * 32;
  const int tx = threadIdx.x & 31, ty = threadIdx.x >> 5;   // ty 0..7
  const float* src = in + (size_t)b * C * L;
  #pragma unroll
  for (int i = 0; i < 4; i++)
    tile[ty + 8 * i][tx] = src[(size_t)(c0 + ty + 8 * i) * L + l0 + tx];
  __syncthreads();
  __bf16* dst = out + (size_t)b * L * C;
  #pragma unroll
  for (int i = 0; i < 4; i++)
    dst[(size_t)(l0 + ty + 8 * i) * C + c0 + tx] = (__bf16)tile[tx][ty + 8 * i];
}

// ---------------------------------------------------------------------------
// KNN v3: batch-8 sorting-network top-8 on packed u64 keys.
// key = (monotone_u32(d_bits) << 11) | candidate_idx  -> single u64 compare
// is exactly lax.top_k's (d asc, idx asc) order, ties included.
// 64 points/block, 4 threads/point; candidates split 2-way across blockIdx.z
// (P halves to 16 KB -> 4 blocks/CU; grid 1024 vs 512 before).
// Interleaved assignment c = 4j + t keeps the 4 lane-addresses of a point in
// consecutive 16B chunks (conflict-free b128 reads, broadcast across points).
// Per 8-candidate batch: Batcher sort-8 (19 CE) then bitonic low-8 merge
// into running top-8 (8 min + 12 CE) -- cost is FIXED per batch instead of
// a ~45-instr insert per candidate that fired on ~every wave-step.
// Distance arithmetic bit-identical to reference (__f*_rn, same op order).
// ---------------------------------------------------------------------------
__device__ __forceinline__ void ce(u64k& a, u64k& b) {
  u64k lo = a < b ? a : b;
  u64k hi = a < b ? b : a;
  a = lo; b = hi;
}

__global__ __launch_bounds__(256, 4) void knn_kernel(
    const float* __restrict__ pos1, const float* __restrict__ pos2,
    u64k* __restrict__ part)
{
  __shared__ floatx4 P[1024];      // 16 KB: (x,y,z,r) per candidate (this half)
  __shared__ u64k md[64][33];      // 16.9 KB: 4 sorted key-lists per point (+pad)
  const int b = blockIdx.y;
  const int half = blockIdx.z;
  const int n0 = blockIdx.x * 64;
  const int tid = threadIdx.x;
  const int cbase = half * 1024;

  const float* p2 = pos2 + b * 3 * M_;
  for (int i = tid; i < 1024; i += 256) {
    const int c = cbase + i;
    float x = p2[c], y = p2[M_ + c], z = p2[2 * M_ + c];
    floatx4 q;
    q[0] = x; q[1] = y; q[2] = z;
    q[3] = __fadd_rn(__fadd_rn(__fmul_rn(x, x), __fmul_rn(y, y)), __fmul_rn(z, z));
    P[i] = q;
  }
  __syncthreads();

  const int p = tid >> 2, t = tid & 3;
  const int n = n0 + p;
  const float* p1 = pos1 + b * 3 * N_;
  const float x1 = p1[n], y1 = p1[N_ + n], z1 = p1[2 * N_ + n];
  const float r1 = __fadd_rn(__fadd_rn(__fmul_rn(x1, x1), __fmul_rn(y1, y1)),
                             __fmul_rn(z1, z1));

  u64k bd[8];
  #pragma unroll
  for (int r = 0; r < 8; r++) bd[r] = ~0ULL;   // sentinel > any real key

  for (int bb = 0; bb < 32; ++bb) {
    // load 8 candidates (interleaved stream: local idx 4*(8*bb+i)+t)
    floatx4 q[8];
    #pragma unroll
    for (int i = 0; i < 8; i++) q[i] = P[4 * (8 * bb + i) + t];

    u64k s[8];
    #pragma unroll
    for (int i = 0; i < 8; i++) {
      float dot = __fadd_rn(__fadd_rn(__fmul_rn(x1, q[i][0]), __fmul_rn(y1, q[i][1])),
                            __fmul_rn(z1, q[i][2]));
      float d = __fsub_rn(__fadd_rn(r1, q[i][3]), __fmul_rn(2.0f, dot));
      unsigned du = __float_as_uint(d);
      unsigned k32 = du ^ ((unsigned)((int)du >> 31) | 0x80000000u);  // monotone
      s[i] = ((u64k)k32 << 11) | (unsigned)(cbase + 4 * (8 * bb + i) + t);
    }

    // Batcher odd-even mergesort, 8 elements, 19 comparators
    ce(s[0], s[1]); ce(s[2], s[3]); ce(s[4], s[5]); ce(s[6], s[7]);
    ce(s[0], s[2]); ce(s[1], s[3]); ce(s[4], s[6]); ce(s[5], s[7]);
    ce(s[1], s[2]); ce(s[5], s[6]);
    ce(s[0], s[4]); ce(s[1], s[5]); ce(s[2], s[6]); ce(s[3], s[7]);
    ce(s[2], s[4]); ce(s[3], s[5]);
    ce(s[1], s[2]); ce(s[3], s[4]); ce(s[5], s[6]);

    if (s[0] < bd[7]) {            // any batch candidate can enter top-8
      // bitonic low-8 of merge(bd asc, s asc): min cross-stage ...
      #pragma unroll
      for (int k = 0; k < 8; k++) { u64k x = s[7 - k]; bd[k] = bd[k] < x ? bd[k] : x; }
      // ... then bitonic-merge-8 clean (dist 4, 2, 1)
      ce(bd[0], bd[4]); ce(bd[1], bd[5]); ce(bd[2], bd[6]); ce(bd[3], bd[7]);
      ce(bd[0], bd[2]); ce(bd[1], bd[3]); ce(bd[4], bd[6]); ce(bd[5], bd[7]);
      ce(bd[0], bd[1]); ce(bd[2], bd[3]); ce(bd[4], bd[5]); ce(bd[6], bd[7]);
    }
  }

  #pragma unroll
  for (int r = 0; r < 8; r++) md[p][t * 8 + r] = bd[r];
  __syncthreads();

  // 4-way merge of sorted key-lists (h <= 7 always within 8 rounds, no guards;
  // real keys are globally unique and < ~0ULL, so the ==m increment is exact)
  if (tid < 64) {
    int h0 = 0, h1 = 0, h2 = 0, h3 = 0;
    u64k* o = part + ((size_t)((b * 2 + half) * N_ + n0 + tid)) * 8;
    #pragma unroll
    for (int r = 0; r < 8; r++) {
      u64k k0 = md[tid][h0], k1 = md[tid][8 + h1];
      u64k k2 = md[tid][16 + h2], k3 = md[tid][24 + h3];
      u64k m01 = k0 < k1 ? k0 : k1;
      u64k m23 = k2 < k3 ? k2 : k3;
      u64k m = m01 < m23 ? m01 : m23;
      h0 += (k0 == m); h1 += (k1 == m); h2 += (k2 == m); h3 += (k3 == m);
      o[r] = m;
    }
  }
}

// ---------------------------------------------------------------------------
// Merge the two candidate-half sorted-8 key lists -> final neighbor indices.
// Bitonic low-8 merge (static indices only). idx = key & 2047.
// ---------------------------------------------------------------------------
__global__ __launch_bounds__(256) void knn_merge(
    const u64k* __restrict__ part, int* __restrict__ idx_out)
{
  const int pt = blockIdx.x * 256 + threadIdx.x;     // 0..32767
  const int b = pt >> 13, n = pt & (N_ - 1);
  const u64k* a0 = part + ((size_t)((b * 2 + 0) * N_ + n)) * 8;
  const u64k* a1 = part + ((size_t)((b * 2 + 1) * N_ + n)) * 8;
  u64k av[8], cv[8];
  #pragma unroll
  for (int r = 0; r < 8; r++) { av[r] = a0[r]; cv[r] = a1[r]; }
  #pragma unroll
  for (int k = 0; k < 8; k++) { u64k x = cv[7 - k]; av[k] = av[k] < x ? av[k] : x; }
  ce(av[0], av[4]); ce(av[1], av[5]); ce(av[2], av[6]); ce(av[3], av[7]);
  ce(av[0], av[2]); ce(av[1], av[3]); ce(av[4], av[6]); ce(av[5], av[7]);
  ce(av[0], av[1]); ce(av[2], av[3]); ce(av[4], av[5]); ce(av[6], av[7]);
  int* o = idx_out + (size_t)pt * 8;
  #pragma unroll
  for (int r = 0; r < 8; r++) o[r] = (int)(av[r] & 2047u);
}

// ---------------------------------------------------------------------------
// LDS-input MFMA layer with next-kstep register prefetch (weights global,
// X from LDS). W-major: D rows = out cols, D cols = points. PT=4 x WT=2,
// weights read once per block. Packed bf16x4 epilogue.
// Fragment maps (gfx950, HW-verified): A[m=lane&15][k=quad*8+j],
// B[n=lane&15][k=quad*8+j], D[row=quad*4+reg][col=lane&15].
// ---------------------------------------------------------------------------
template <int KSTEPS>
__device__ __forceinline__ void mfma_layer_lds(
    const __bf16* X, const __bf16* W, int wstride,
    const float* sv, const float* bv,
    __bf16* Y, int ycolbase, int c0, int lane)
{
  const int lrow = lane & 15, quad = lane >> 4;
  floatx4 acc[4][2];
  const floatx4 fz = {0.f, 0.f, 0.f, 0.f};
  #pragma unroll
  for (int pt = 0; pt < 4; pt++) { acc[pt][0] = fz; acc[pt][1] = fz; }

  bf16x8 wf0 = *(const bf16x8*)(W + (size_t)(c0 + lrow) * wstride + quad * 8);
  bf16x8 wf1 = *(const bf16x8*)(W + (size_t)(c0 + 16 + lrow) * wstride + quad * 8);
  bf16x8 xf[4];
  #pragma unroll
  for (int pt = 0; pt < 4; pt++)
    xf[pt] = *(const bf16x8*)(X + (pt * 16 + lrow) * 136 + quad * 8);

  #pragma unroll
  for (int ks = 0; ks < KSTEPS; ks++) {
    bf16x8 wn0, wn1, xn[4];
    if (ks + 1 < KSTEPS) {
      const int kn = (ks + 1) * 32 + quad * 8;
      wn0 = *(const bf16x8*)(W + (size_t)(c0 + lrow) * wstride + kn);
      wn1 = *(const bf16x8*)(W + (size_t)(c0 + 16 + lrow) * wstride + kn);
      #pragma unroll
      for (int pt = 0; pt < 4; pt++)
        xn[pt] = *(const bf16x8*)(X + (pt * 16 + lrow) * 136 + kn);
    }
    #pragma unroll
    for (int pt = 0; pt < 4; pt++) {
      acc[pt][0] = __builtin_amdgcn_mfma_f32_16x16x32_bf16(wf0, xf[pt], acc[pt][0], 0, 0, 0);
      acc[pt][1] = __builtin_amdgcn_mfma_f32_16x16x32_bf16(wf1, xf[pt], acc[pt][1], 0, 0, 0);
    }
    if (ks + 1 < KSTEPS) {
      wf0 = wn0; wf1 = wn1;
      #pragma unroll
      for (int pt = 0; pt < 4; pt++) xf[pt] = xn[pt];
    }
  }

  #pragma unroll
  for (int pt = 0; pt < 4; pt++) {
    #pragma unroll
    for (int wt = 0; wt < 2; wt++) {
      const int colg = c0 + wt * 16 + quad * 4;    // 4 consecutive out cols
      floatx4 s4 = *(const floatx4*)(sv + colg);
      floatx4 b4 = *(const floatx4*)(bv + colg);
      bf16x4 pk;
      #pragma unroll
      for (int r = 0; r < 4; r++) {
        float v = acc[pt][wt][r] * s4[r] + b4[r];
        pk[r] = (__bf16)(v > 0.f ? v : 0.f);
      }
      *(bf16x4*)(Y + (pt * 16 + lrow) * 136 + (colg - ycolbase)) = pk;
    }
  }
}

// ---------------------------------------------------------------------------
// MLP1 v2: all 64 gathered f2t rows are STAGED ONCE into LDS (32 KB) via
// global_load_lds width-16 at block start. DMA dest linear; conflict-free
// reads via XOR-swizzled per-lane GLOBAL source chunk (row&7) + same XOR on
// the ds_read_b128 side. Y1 aliases the X stage (dead after L0).
// ---------------------------------------------------------------------------
__global__ __launch_bounds__(256, 3) void mlp1_kernel(
    const float* __restrict__ pos1, const float* __restrict__ pos2,
    const int* __restrict__ idx, const __bf16* __restrict__ f2t,
    const __bf16* __restrict__ w0p, const float* __restrict__ s10, const float* __restrict__ b10,
    const __bf16* __restrict__ w11b, const float* __restrict__ s11, const float* __restrict__ b11,
    const __bf16* __restrict__ w12b, const float* __restrict__ s12, const float* __restrict__ b12,
    __bf16* __restrict__ maxed)
{
  __shared__ __align__(16) __bf16 Xs[64 * 256];   // 32 KB staged gathers (swizzled); Y1 aliases
  __shared__ __align__(16) __bf16 Y0[64 * 136];   // 17.4 KB
  __shared__ int mrow[64];
  __shared__ __align__(16) float dp[64][4];
  __bf16* const Y1 = Xs;                          // X dead after L0

  const int b = blockIdx.y;
  const int n0 = blockIdx.x * 8;
  const int tid = threadIdx.x;
  const int wave = tid >> 6, lane = tid & 63;
  const int lrow = lane & 15, quad = lane >> 4;
  const int c0 = 32 * wave;

  // prologue: neighbor index + posdiff per row (row r = point g, rank k)
  if (tid < 64) {
    const int r = tid, g = r >> 3;
    const int m = idx[(b * N_ + n0) * K_ + r];
    mrow[r] = m;
    const int n = n0 + g;
    dp[r][0] = pos2[b * 3 * M_ + m]          - pos1[b * 3 * N_ + n];
    dp[r][1] = pos2[b * 3 * M_ + M_ + m]     - pos1[b * 3 * N_ + N_ + n];
    dp[r][2] = pos2[b * 3 * M_ + 2 * M_ + m] - pos1[b * 3 * N_ + 2 * N_ + n];
    dp[r][3] = 0.f;
  }
  __syncthreads();

  // ---- stage: wave w DMAs rows [16w,16w+16) of the gather into Xs.
  // Per instr: lanes 0-31 = row r, lanes 32-63 = row r+1 (1 KB linear dest).
  // Source chunk index XORed by (row&7) so swizzled reads are conflict-free.
  {
    const int r0 = wave * 16;
    const int half = lane >> 5;          // which row of the pair
    const int ch = lane & 31;            // 16B chunk within the 512B row
    #pragma unroll
    for (int i = 0; i < 8; i++) {
      const int r = r0 + 2 * i + half;
      const int m = mrow[r];
      const char* src = (const char*)f2t
          + (((size_t)(b * M_ + m)) << 9)
          + ((ch << 4) ^ ((r & 7) << 4));
      __builtin_amdgcn_global_load_lds(
          (const __attribute__((address_space(1))) unsigned int*)src,
          (__attribute__((address_space(3))) unsigned int*)(Xs + (r0 + 2 * i) * 256),
          16, 0, 0);
    }
  }

  // last k-step fragment (posdiff) built in registers while DMA in flight
  bf16x8 xlast[4];
  #pragma unroll
  for (int pt = 0; pt < 4; pt++) {
    bf16x8 v = {};
    if (quad == 0) {               // k=256..263: [dx,dy,dz,0,...]
      floatx4 d = *(const floatx4*)(&dp[pt * 16 + lrow][0]);
      v[0] = (__bf16)d[0]; v[1] = (__bf16)d[1]; v[2] = (__bf16)d[2];
    }
    xlast[pt] = v;                 // quads 1-3 zero (w0p zero-padded too)
  }

  // W k-step-0 fragments issued before the barrier (L1/L2-resident)
  bf16x8 wf0 = *(const bf16x8*)(w0p + (size_t)(c0 + lrow) * 288 + quad * 8);
  bf16x8 wf1 = *(const bf16x8*)(w0p + (size_t)(c0 + 16 + lrow) * 288 + quad * 8);

  __syncthreads();                 // drains the global_load_lds DMA

  // ---- L0: K=288 = 8 LDS ksteps + posdiff step. Out -> Y0.
  {
    floatx4 acc[4][2];
    const floatx4 fz = {0.f, 0.f, 0.f, 0.f};
    #pragma unroll
    for (int pt = 0; pt < 4; pt++) { acc[pt][0] = fz; acc[pt][1] = fz; }

    const int swz = (lrow & 7) << 4;     // byte XOR within a 512B row
    bf16x8 xf[4];
    #pragma unroll
    for (int pt = 0; pt < 4; pt++)
      xf[pt] = *(const bf16x8*)((const char*)Xs + (pt * 16 + lrow) * 512
                                + ((quad * 16) ^ swz));

    #pragma unroll
    for (int ks = 0; ks < 9; ks++) {
      bf16x8 wn0, wn1, xn[4];
      if (ks < 8) {
        const int kn = (ks + 1) * 32 + quad * 8;
        wn0 = *(const bf16x8*)(w0p + (size_t)(c0 + lrow) * 288 + kn);
        wn1 = *(const bf16x8*)(w0p + (size_t)(c0 + 16 + lrow) * 288 + kn);
        if (ks < 7) {
          const int kb = ((ks + 1) * 64 + quad * 16) ^ swz;
          #pragma unroll
          for (int pt = 0; pt < 4; pt++)
            xn[pt] = *(const bf16x8*)((const char*)Xs + (pt * 16 + lrow) * 512 + kb);
        } else {
          #pragma unroll
          for (int pt = 0; pt < 4; pt++) xn[pt] = xlast[pt];
        }
      }
      #pragma unroll
      for (int pt = 0; pt < 4; pt++) {
        acc[pt][0] = __builtin_amdgcn_mfma_f32_16x16x32_bf16(wf0, xf[pt], acc[pt][0], 0, 0, 0);
        acc[pt][1] = __builtin_amdgcn_mfma_f32_16x16x32_bf16(wf1, xf[pt], acc[pt][1], 0, 0, 0);
      }
      if (ks < 8) {
        wf0 = wn0; wf1 = wn1;
        #pragma unroll
        for (int pt = 0; pt < 4; pt++) xf[pt] = xn[pt];
      }
    }
    #pragma unroll
    for (int pt = 0; pt < 4; pt++) {
      #pragma unroll
      for (int wt = 0; wt < 2; wt++) {
        const int colg = c0 + wt * 16 + quad * 4;
        floatx4 s4 = *(const floatx4*)(s10 + colg);
        floatx4 b4 = *(const floatx4*)(b10 + colg);
        bf16x4 pk;
        #pragma unroll
        for (int r = 0; r < 4; r++) {
          float v = acc[pt][wt][r] * s4[r] + b4[r];
          pk[r] = (__bf16)(v > 0.f ? v : 0.f);
        }
        *(bf16x4*)(Y0 + (pt * 16 + lrow) * 136 + colg) = pk;
      }
    }
  }
  __syncthreads();

  // ---- L1: 128 -> 128, Y0 -> Y1 (aliases the now-dead X stage)
  mfma_layer_lds<4>(Y0, w11b, 128, s11, b11, Y1, 0, c0, lane);
  __syncthreads();

  // ---- L2: 128 -> 256 in two 128-col passes (out -> Y0), maxpool K=8
  #pragma unroll
  for (int p = 0; p < 2; p++) {
    mfma_layer_lds<4>(Y1, w12b, 128, s12, b12, Y0, 128 * p, 128 * p + c0, lane);
    __syncthreads();
    // vectorized maxpool: 128 threads x 8 cols, b128 LDS reads + 16B store
    if (tid < 128) {
      const int g = tid >> 4, cb = (tid & 15) * 8;
      bf16x8 v0 = *(const bf16x8*)(Y0 + (g * 8) * 136 + cb);
      float fmx[8];
      #pragma unroll
      for (int j = 0; j < 8; j++) fmx[j] = (float)v0[j];
      #pragma unroll
      for (int k = 1; k < 8; k++) {
        bf16x8 v = *(const bf16x8*)(Y0 + (g * 8 + k) * 136 + cb);
        #pragma unroll
        for (int j = 0; j < 8; j++) {
          float f = (float)v[j];
          fmx[j] = f > fmx[j] ? f : fmx[j];
        }
      }
      bf16x8 o;
      #pragma unroll
      for (int j = 0; j < 8; j++) o[j] = (__bf16)fmx[j];
      *(bf16x8*)(maxed + ((size_t)(b * N_ + n0 + g)) * 256 + 128 * p + cb) = o;
    }
    __syncthreads();
  }
}

// ---------------------------------------------------------------------------
// MLP2: 32 rows x 128 out-cols per block, grid (1024, 2) = 2048 blocks.
// A = [maxed|f1t] bf16 contiguous, B = w20b [256][512]. Next-kstep register
// prefetch. Out fp32 floatx4.
// ---------------------------------------------------------------------------
__global__ __launch_bounds__(256, 6) void mlp2_kernel(
    const __bf16* __restrict__ maxed, const __bf16* __restrict__ f1t,
    const __bf16* __restrict__ w20b, const float* __restrict__ s20,
    const float* __restrict__ b20, float* __restrict__ out)
{
  const int rows0 = blockIdx.x * 32;           // b*N + n
  const int b = rows0 >> 13;
  const int nbase = rows0 & (N_ - 1);
  const int tid = threadIdx.x;
  const int wave = tid >> 6, lane = tid & 63;
  const int lrow = lane & 15, quad = lane >> 4;
  const int c0 = 128 * blockIdx.y + 32 * wave;
  const floatx4 fz = {0.f, 0.f, 0.f, 0.f};

  floatx4 acc[2][2];
  acc[0][0] = fz; acc[0][1] = fz; acc[1][0] = fz; acc[1][1] = fz;

  auto aptr = [&](int ks, int mt) -> const __bf16* {
    const int k = ks * 32 + quad * 8;
    return (ks < 8) ? (maxed + (size_t)(rows0 + mt * 16 + lrow) * 256 + k)
                    : (f1t + (size_t)(rows0 + mt * 16 + lrow) * 256 + (k - 256));
  };

  bf16x8 w0 = *(const bf16x8*)(w20b + (size_t)(c0 + lrow) * 512 + quad * 8);
  bf16x8 w1 = *(const bf16x8*)(w20b + (size_t)(c0 + 16 + lrow) * 512 + quad * 8);
  bf16x8 a0 = *(const bf16x8*)aptr(0, 0);
  bf16x8 a1 = *(const bf16x8*)aptr(0, 1);

  #pragma unroll
  for (int ks = 0; ks < 16; ks++) {
    bf16x8 wn0, wn1, an0, an1;
    if (ks < 15) {
      const int kn = (ks + 1) * 32 + quad * 8;
      wn0 = *(const bf16x8*)(w20b + (size_t)(c0 + lrow) * 512 + kn);
      wn1 = *(const bf16x8*)(w20b + (size_t)(c0 + 16 + lrow) * 512 + kn);
      an0 = *(const bf16x8*)aptr(ks + 1, 0);
      an1 = *(const bf16x8*)aptr(ks + 1, 1);
    }
    acc[0][0] = __builtin_amdgcn_mfma_f32_16x16x32_bf16(a0, w0, acc[0][0], 0, 0, 0);
    acc[0][1] = __builtin_amdgcn_mfma_f32_16x16x32_bf16(a0, w1, acc[0][1], 0, 0, 0);
    acc[1][0] = __builtin_amdgcn_mfma_f32_16x16x32_bf16(a1, w0, acc[1][0], 0, 0, 0);
    acc[1][1] = __builtin_amdgcn_mfma_f32_16x16x32_bf16(a1, w1, acc[1][1], 0, 0, 0);
    if (ks < 15) { w0 = wn0; w1 = wn1; a0 = an0; a1 = an1; }
  }

  #pragma unroll
  for (int ct = 0; ct < 2; ct++) {
    const int col = c0 + ct * 16 + lrow;
    const float s = s20[col];
    const float bb = b20[col];
    #pragma unroll
    for (int mt = 0; mt < 2; mt++) {
      floatx4 pk;
      #pragma unroll
      for (int r = 0; r < 4; r++) {
        float v = acc[mt][ct][r] * s + bb;
        pk[r] = v > 0.f ? v : 0.f;
      }
      const int n = nbase + mt * 16 + quad * 4;
      *(floatx4*)(out + ((size_t)(b * 256 + col)) * N_ + n) = pk;
    }
  }
}

// ---------------------------------------------------------------------------
extern "C" void kernel_launch(void* const* d_in, const int* in_sizes, int n_in,
                              void* d_out, int out_size, void* d_ws, size_t ws_size,
                              hipStream_t stream)
{
  const float* pos1     = (const float*)d_in[0];
  const float* pos2     = (const float*)d_in[1];
  const float* feature1 = (const float*)d_in[2];
  const float* feature2 = (const float*)d_in[3];
  const float* w1_0 = (const float*)d_in[4];
  const float* s1_0 = (const float*)d_in[5];
  const float* b1_0 = (const float*)d_in[6];
  const float* w1_1 = (const float*)d_in[7];
  const float* s1_1 = (const float*)d_in[8];
  const float* b1_1 = (const float*)d_in[9];
  const float* w1_2 = (const float*)d_in[10];
  const float* s1_2 = (const float*)d_in[11];
  const float* b1_2 = (const float*)d_in[12];
  const float* w2_0 = (const float*)d_in[13];
  const float* s2_0 = (const float*)d_in[14];
  const float* b2_0 = (const float*)d_in[15];

  // Workspace layout (39,231,488 B total)
  char* ws = (char*)d_ws;
  int*    idx   = (int*)(ws);                    //  1,048,576 @ 0
  __bf16* f2t   = (__bf16*)(ws + 1048576);       //  4,194,304
  __bf16* f1t   = (__bf16*)(ws + 5242880);       // 16,777,216
  __bf16* maxed = (__bf16*)(ws + 22020096);      // 16,777,216
  __bf16* w0p   = (__bf16*)(ws + 38797312);      //     73,728
  __bf16* w11b  = (__bf16*)(ws + 38871040);      //     32,768
  __bf16* w12b  = (__bf16*)(ws + 38903808);      //     65,536
  __bf16* w20b  = (__bf16*)(ws + 38969344);      //    262,144
  // knn partial key lists (4 MB) live in maxed's region: knn + knn_merge
  // complete (stream-ordered) before mlp1 writes maxed.
  u64k*   part  = (u64k*)(ws + 22020096);

  prep_weights<<<dim3(848), 256, 0, stream>>>(w1_0, w1_1, w1_2, w2_0,
                                              w0p, w11b, w12b, w20b);
  transpose_cast<<<dim3(M_ / 32, 8, B_), 256, 0, stream>>>(feature2, f2t, 256, M_);
  transpose_cast<<<dim3(N_ / 32, 8, B_), 256, 0, stream>>>(feature1, f1t, 256, N_);
  knn_kernel<<<dim3(N_ / 64, B_, 2), 256, 0, stream>>>(pos1, pos2, part);
  knn_merge<<<dim3(N_ * B_ / 256), 256, 0, stream>>>(part, idx);
  mlp1_kernel<<<dim3(N_ / 8, B_), 256, 0, stream>>>(
      pos1, pos2, idx, f2t, w0p, s1_0, b1_0, w11b, s1_1, b1_1, w12b, s1_2, b1_2, maxed);
  mlp2_kernel<<<dim3(1024, 2), 256, 0, stream>>>(maxed, f1t, w20b, s2_0, b2_0,
                                                 (float*)d_out);
}